// Round 6
// baseline (455.279 us; speedup 1.0000x reference)
//
#include <hip/hip_runtime.h>

// GraphFilter B=16,T=64,F=64,N=128,E=2,K=4 — transposed fused chain (v4).
// Transposed state Z = W^T (N x F). Per (b,t), per e:
//   Z = U3^T[t-3]
//   Z = U2^T[t-2] + S^T[t-2]@Z
//   Z = U1^T[t-1] + S^T[t-1]@Z
//   Y^T += U0^T[t] + S^T[t]@Z        (accumulated over e)
// with U_k^T[n][o] = sum_f xT[s][n][f] * H[o,e,k,f].
// MFMA roles: A = S^T (ST buffer, m-contig) or xT (f-contig); B = Z (wave-
// private LDS, [o_local][m]) or Hb ([o][f]).  D[row=n][col=o].  Each wave owns
// o in [16w,16w+16) for full n=0..127 -> Z hand-off never crosses waves: no
// __syncthreads in the chain at all.

namespace {
constexpr int B = 16, T = 64, F = 64, N = 128, E = 2, K = 4;
constexpr int SZ = 136;   // sZ row stride (ushorts)
}

typedef short v8s __attribute__((ext_vector_type(8)));
typedef float v4f __attribute__((ext_vector_type(4)));

__device__ inline ushort f2bf(float f) {
  union { float f; uint u; } v; v.f = f;
  uint u = v.u;
  return (ushort)((u + 0x7fffu + ((u >> 16) & 1u)) >> 16);
}

__device__ inline uint pk2(float a, float b) {
  return (uint)f2bf(a) | ((uint)f2bf(b) << 16);
}

// ---- prep: cvt_S (2048 blocks) + cvt_X (1024) + cvt_H (32) in one launch ----
__global__ __launch_bounds__(256) void gf_prep(
    const float* __restrict__ x, const float* __restrict__ S,
    const float* __restrict__ H, ushort* __restrict__ xT,
    ushort* __restrict__ ST, ushort* __restrict__ Hb) {
  __shared__ ushort tile[128 * 128];   // 32 KB
  const int bid = blockIdx.x;
  const int tid = threadIdx.x;

  if (bid < B * T * E) {
    // ---- S: fp32 [m][n] -> bf16 [n][m], swizzled vector transpose ----
    const float* Sg = S + (size_t)bid * N * N;
    ushort* Og = ST + (size_t)bid * N * N;
    #pragma unroll
    for (int it = 0; it < 8; ++it) {
      const int idx = tid + it * 256;    // (m, g)
      const int m = idx >> 4, g = idx & 15;
      const float4 v0 = *(const float4*)(Sg + m * N + g * 8);
      const float4 v1 = *(const float4*)(Sg + m * N + g * 8 + 4);
      uint4 w;
      w.x = pk2(v0.x, v0.y); w.y = pk2(v0.z, v0.w);
      w.z = pk2(v1.x, v1.y); w.w = pk2(v1.z, v1.w);
      const int gp = g ^ (m >> 3);
      *(uint4*)&tile[m * 128 + gp * 8] = w;
    }
    __syncthreads();
    const int a = tid & 15, b = tid >> 4;
    v8s rows[8];
    #pragma unroll
    for (int j = 0; j < 8; ++j)
      rows[j] = *(const v8s*)&tile[(8 * a + j) * 128 + ((b ^ a) * 8)];
    #pragma unroll
    for (int i = 0; i < 8; ++i) {
      uint4 w;
      w.x = (uint)(ushort)rows[0][i] | ((uint)(ushort)rows[1][i] << 16);
      w.y = (uint)(ushort)rows[2][i] | ((uint)(ushort)rows[3][i] << 16);
      w.z = (uint)(ushort)rows[4][i] | ((uint)(ushort)rows[5][i] << 16);
      w.w = (uint)(ushort)rows[6][i] | ((uint)(ushort)rows[7][i] << 16);
      *(uint4*)(Og + (8 * b + i) * N + 8 * a) = w;
    }
  } else if (bid < B * T * E + B * T) {
    // ---- x: fp32 [f][n] -> bf16 xT [n][f] ----
    const int xb = bid - B * T * E;
    const float* xg = x + (size_t)xb * F * N;
    ushort* Og = xT + (size_t)xb * N * F;
    #pragma unroll
    for (int it = 0; it < 4; ++it) {
      const int idx = tid + it * 256;    // (f, g)
      const int f = idx >> 4, g = idx & 15;
      const float4 v0 = *(const float4*)(xg + f * N + g * 8);
      const float4 v1 = *(const float4*)(xg + f * N + g * 8 + 4);
      uint4 w;
      w.x = pk2(v0.x, v0.y); w.y = pk2(v0.z, v0.w);
      w.z = pk2(v1.x, v1.y); w.w = pk2(v1.z, v1.w);
      const int gp = g ^ (f >> 3);
      *(uint4*)&tile[f * 128 + gp * 8] = w;
    }
    __syncthreads();
    if (tid < 128) {
      const int a = tid & 7, b = tid >> 3;
      v8s rows[8];
      #pragma unroll
      for (int j = 0; j < 8; ++j)
        rows[j] = *(const v8s*)&tile[(8 * a + j) * 128 + ((b ^ a) * 8)];
      #pragma unroll
      for (int i = 0; i < 8; ++i) {
        uint4 w;
        w.x = (uint)(ushort)rows[0][i] | ((uint)(ushort)rows[1][i] << 16);
        w.y = (uint)(ushort)rows[2][i] | ((uint)(ushort)rows[3][i] << 16);
        w.z = (uint)(ushort)rows[4][i] | ((uint)(ushort)rows[5][i] << 16);
        w.w = (uint)(ushort)rows[6][i] | ((uint)(ushort)rows[7][i] << 16);
        *(uint4*)(Og + (8 * b + i) * F + 8 * a) = w;
      }
    }
  } else {
    // ---- H: fp32 [o][e][k][f] -> bf16 [e][k][o][f] ----
    const int hb = bid - (B * T * E + B * T);
    const int d = (hb * 256 + tid) * 4;
    const int f = d & 63, o = (d >> 6) & 63, k = (d >> 12) & 3, e = (d >> 14) & 1;
    const float4 v = *(const float4*)(H + (((size_t)o * E + e) * K + k) * F + f);
    uint2 w;
    w.x = pk2(v.x, v.y);
    w.y = pk2(v.z, v.w);
    *(uint2*)(Hb + d) = w;
  }
}

// ---- fused transposed chain: one block per (b,t), wave w owns o=16w..16w+15 ----
__global__ __launch_bounds__(256, 4) void gf_chain(
    const ushort* __restrict__ xT, const ushort* __restrict__ ST,
    const ushort* __restrict__ Hb, const float* __restrict__ bias,
    float* __restrict__ y) {
  __shared__ ushort sZs[4][16 * SZ];   // 17.4 KB, wave-private slices
  const int bid = blockIdx.x;          // b*T + t
  const int t = bid & (T - 1);
  const int tid = threadIdx.x, w = tid >> 6, lane = tid & 63;
  const int l15 = lane & 15, q = lane >> 4;
  ushort* sZ = sZs[w];
  const int o = w * 16 + l15;          // this lane's output column

  v4f yacc[8];
  #pragma unroll
  for (int i = 0; i < 8; ++i) {
    yacc[i][0] = 0.f; yacc[i][1] = 0.f; yacc[i][2] = 0.f; yacc[i][3] = 0.f;
  }

  for (int e = 0; e < E; ++e) {
    v4f acc[8];
    bool have = false;
    #pragma unroll
    for (int tap = 3; tap >= 0; --tap) {
      const int s = t - tap;
      if (s < 0) continue;
      const bool doMM = have;
      // spill Z_prev (acc) to wave-private LDS as bf16 [o_local][n]
      if (doMM) {
        __builtin_amdgcn_wave_barrier();
        #pragma unroll
        for (int mt = 0; mt < 8; ++mt) {
          uint2 wv;
          wv.x = pk2(acc[mt][0], acc[mt][1]);
          wv.y = pk2(acc[mt][2], acc[mt][3]);
          *(uint2*)&sZ[l15 * SZ + mt * 16 + q * 4] = wv;
        }
        __builtin_amdgcn_wave_barrier();
      }
      v4f* const tgt = (tap == 0) ? yacc : acc;
      if (tap != 0) {
        #pragma unroll
        for (int mt = 0; mt < 8; ++mt) {
          tgt[mt][0] = 0.f; tgt[mt][1] = 0.f; tgt[mt][2] = 0.f; tgt[mt][3] = 0.f;
        }
      }
      // mm: tgt += S^T[s] @ Z   (A from global ST, B from wave-private sZ)
      if (doMM) {
        const ushort* Sg = ST + ((size_t)(bid - tap) * E + e) * (N * N);
        #pragma unroll
        for (int c = 0; c < 4; ++c) {
          const v8s bz = *(const v8s*)&sZ[l15 * SZ + c * 32 + q * 8];
          #pragma unroll
          for (int mt = 0; mt < 8; ++mt) {
            const v8s af = *(const v8s*)(Sg + (mt * 16 + l15) * N + c * 32 + q * 8);
            tgt[mt] = __builtin_amdgcn_mfma_f32_16x16x32_bf16(af, bz, tgt[mt], 0, 0, 0);
          }
        }
      }
      // proj: tgt += U_tap^T[s]  (A from xT, B from Hb)
      {
        const ushort* hrow = Hb + ((size_t)((e * K + tap) * 64) + o) * 64;
        const v8s bh0 = *(const v8s*)(hrow + q * 8);
        const v8s bh1 = *(const v8s*)(hrow + 32 + q * 8);
        const ushort* xrow = xT + (size_t)(bid - tap) * (N * F);
        #pragma unroll
        for (int mt = 0; mt < 8; ++mt) {
          const ushort* xr = xrow + (mt * 16 + l15) * F;
          const v8s ax0 = *(const v8s*)(xr + q * 8);
          const v8s ax1 = *(const v8s*)(xr + 32 + q * 8);
          tgt[mt] = __builtin_amdgcn_mfma_f32_16x16x32_bf16(ax0, bh0, tgt[mt], 0, 0, 0);
          tgt[mt] = __builtin_amdgcn_mfma_f32_16x16x32_bf16(ax1, bh1, tgt[mt], 0, 0, 0);
        }
      }
      have = true;
    }
  }

  // epilogue: y[b,t][o][n] = Y^T[n][o] + bias[o]; reg r <-> consecutive n
  const float bv = bias[o];
  float* yg = y + (size_t)bid * F * N + (size_t)o * N;
  #pragma unroll
  for (int mt = 0; mt < 8; ++mt) {
    float4 v;
    v.x = yacc[mt][0] + bv; v.y = yacc[mt][1] + bv;
    v.z = yacc[mt][2] + bv; v.w = yacc[mt][3] + bv;
    *(float4*)(yg + mt * 16 + q * 4) = v;
  }
}

extern "C" void kernel_launch(void* const* d_in, const int* in_sizes, int n_in,
                              void* d_out, int out_size, void* d_ws, size_t ws_size,
                              hipStream_t stream) {
  const float* x    = (const float*)d_in[0];
  const float* S    = (const float*)d_in[1];
  const float* H    = (const float*)d_in[2];
  const float* bias = (const float*)d_in[3];
  float* y = (float*)d_out;

  const size_t STn = (size_t)B * T * E * N * N;   // 33.55M ushorts (64 MB)
  const size_t XTn = (size_t)B * T * N * F;       //  8.39M ushorts (16 MB)
  ushort* ST = (ushort*)d_ws;
  ushort* xT = ST + STn;
  ushort* Hb = xT + XTn;                          // 32768 ushorts

  gf_prep <<<B * T * E + B * T + 32, 256, 0, stream>>>(x, S, H, xT, ST, Hb);
  gf_chain<<<B * T,                  256, 0, stream>>>(xT, ST, Hb, bias, y);
}

// Round 7
// 301.483 us; speedup vs baseline: 1.5101x; 1.5101x over previous
//
#include <hip/hip_runtime.h>

// GraphFilter B=16,T=64,F=64,N=128,E=2,K=4 — v5: fused transposed chain,
// LDS-staged S with in-kernel transpose, n-split waves.
// State Z = W^T [n][o].  Per (b,t), per e:
//   Z = U3^T[t-3];  Z = U2^T[t-2] + S^T[t-2]@Z;  Z = U1^T[t-1] + S^T[t-1]@Z;
//   Y^T += U0^T[t] + S^T[t]@Z
// U_k^T[n][o] = sum_f xT[s][n][f] H[o,e,k,f].
// Wave w owns n in [32w,32w+32) for ALL o (n-split): S^T/Z fragments come from
// shared LDS with no per-wave duplication; Z hand-off via sZ (+barriers).
// S is transposed fp32->bf16 in-kernel: 3-phase in-place XOR-swizzled LDS
// transpose, all ds_*_b128, conflict-free per quarter-wave (stride 136).

namespace {
constexpr int B = 16, T = 64, F = 64, N = 128, E = 2, K = 4;
constexpr int SSW = 136;  // sS row stride (ushorts)
constexpr int SZW = 136;  // sZ row stride (ushorts)
}

typedef short v8s __attribute__((ext_vector_type(8)));
typedef float v4f __attribute__((ext_vector_type(4)));

__device__ inline ushort f2bf(float f) {
  union { float f; uint u; } v; v.f = f;
  uint u = v.u;
  return (ushort)((u + 0x7fffu + ((u >> 16) & 1u)) >> 16);
}

__device__ inline uint pk2(float a, float b) {
  return (uint)f2bf(a) | ((uint)f2bf(b) << 16);
}

// ---- prep: x fp32 [f][n] -> xT bf16 [n][f]  (+ H -> Hb [e][k][o][f]) ----
__global__ __launch_bounds__(256) void gf_prep(
    const float* __restrict__ x, const float* __restrict__ H,
    ushort* __restrict__ xT, ushort* __restrict__ Hb) {
  __shared__ ushort tile[64 * 128];
  const int bid = blockIdx.x;
  const int tid = threadIdx.x;
  if (bid < B * T) {
    const float* xg = x + (size_t)bid * F * N;
    ushort* Og = xT + (size_t)bid * N * F;
    #pragma unroll
    for (int it = 0; it < 4; ++it) {
      const int idx = tid + it * 256;    // (f, g)
      const int f = idx >> 4, g = idx & 15;
      const float4 v0 = *(const float4*)(xg + f * N + g * 8);
      const float4 v1 = *(const float4*)(xg + f * N + g * 8 + 4);
      uint4 w;
      w.x = pk2(v0.x, v0.y); w.y = pk2(v0.z, v0.w);
      w.z = pk2(v1.x, v1.y); w.w = pk2(v1.z, v1.w);
      const int gp = g ^ (f >> 3);
      *(uint4*)&tile[f * 128 + gp * 8] = w;
    }
    __syncthreads();
    if (tid < 128) {
      const int a = tid & 7, b = tid >> 3;   // a: f-grp, b: n-grp
      v8s rows[8];
      #pragma unroll
      for (int j = 0; j < 8; ++j)
        rows[j] = *(const v8s*)&tile[(8 * a + j) * 128 + ((b ^ a) * 8)];
      #pragma unroll
      for (int i = 0; i < 8; ++i) {
        uint4 w;
        w.x = (uint)(ushort)rows[0][i] | ((uint)(ushort)rows[1][i] << 16);
        w.y = (uint)(ushort)rows[2][i] | ((uint)(ushort)rows[3][i] << 16);
        w.z = (uint)(ushort)rows[4][i] | ((uint)(ushort)rows[5][i] << 16);
        w.w = (uint)(ushort)rows[6][i] | ((uint)(ushort)rows[7][i] << 16);
        *(uint4*)(Og + (8 * b + i) * F + 8 * a) = w;
      }
    }
  } else {
    const int hb = bid - B * T;
    const int d = (hb * 256 + tid) * 4;    // linear over [e][k][o][f]
    const int f = d & 63, o = (d >> 6) & 63, k = (d >> 12) & 3, e = (d >> 14) & 1;
    const float4 v = *(const float4*)(H + (((size_t)o * E + e) * K + k) * F + f);
    uint2 w;
    w.x = pk2(v.x, v.y);
    w.y = pk2(v.z, v.w);
    *(uint2*)(Hb + d) = w;
  }
}

// ---- fused chain: one block per (b,t); wave w owns n in [32w, 32w+32) ----
__global__ __launch_bounds__(256, 3) void gf_chain(
    const float* __restrict__ S, const ushort* __restrict__ xT,
    const ushort* __restrict__ Hb, const float* __restrict__ bias,
    float* __restrict__ y) {
  __shared__ ushort sS[128 * SSW];   // 34.8 KB: S staging + final S^T
  __shared__ ushort sZ[64 * SZW];    // 17.4 KB: Z in B-operand layout [o][n]
  const int bid = blockIdx.x;        // b*T + t
  const int t = bid & (T - 1);
  const int tid = threadIdx.x, w = tid >> 6, lane = tid & 63;
  const int l15 = lane & 15, q = lane >> 4;

  v4f yacc[2][4];
  #pragma unroll
  for (int mt = 0; mt < 2; ++mt)
    #pragma unroll
    for (int ot = 0; ot < 4; ++ot) {
      yacc[mt][ot][0] = 0.f; yacc[mt][ot][1] = 0.f;
      yacc[mt][ot][2] = 0.f; yacc[mt][ot][3] = 0.f;
    }

  for (int e = 0; e < E; ++e) {
    v4f acc[2][4];
    bool have = false;
    #pragma unroll
    for (int tap = 3; tap >= 0; --tap) {
      const int s = t - tap;
      if (s < 0) continue;
      const bool doMM = have;
      const float* Sg = S + (size_t)((bid - tap) * E + e) * (N * N);

      if (doMM) {
        __syncthreads();   // prev mm's sS/sZ readers done
        // spill Z (in acc) -> sZ as [o][n], n contiguous
        #pragma unroll
        for (int mt = 0; mt < 2; ++mt)
          #pragma unroll
          for (int ot = 0; ot < 4; ++ot) {
            uint2 wv;
            wv.x = pk2(acc[mt][ot][0], acc[mt][ot][1]);
            wv.y = pk2(acc[mt][ot][2], acc[mt][ot][3]);
            *(uint2*)&sZ[(ot * 16 + l15) * SZW + (2 * w + mt) * 16 + q * 4] = wv;
          }
        // phase1: S fp32 [m][n] -> sS bf16 [m][n], XOR-swizzled chunks
        #pragma unroll
        for (int half = 0; half < 2; ++half) {
          float4 r0[4], r1[4];
          #pragma unroll
          for (int it = 0; it < 4; ++it) {
            const int idx = tid + (half * 4 + it) * 256;
            const int m = idx >> 4, g = idx & 15;
            r0[it] = *(const float4*)(Sg + m * N + g * 8);
            r1[it] = *(const float4*)(Sg + m * N + g * 8 + 4);
          }
          #pragma unroll
          for (int it = 0; it < 4; ++it) {
            const int idx = tid + (half * 4 + it) * 256;
            const int m = idx >> 4, g = idx & 15;
            uint4 wv;
            wv.x = pk2(r0[it].x, r0[it].y); wv.y = pk2(r0[it].z, r0[it].w);
            wv.z = pk2(r1[it].x, r1[it].y); wv.w = pk2(r1[it].z, r1[it].w);
            *(uint4*)&sS[m * SSW + ((g ^ (m >> 3)) * 8)] = wv;
          }
        }
      }

      // proj: tgt += U_tap^T (global xT / Hb only — independent of LDS)
      v4f (*tgt)[4] = (tap == 0) ? yacc : acc;
      if (tap != 0) {
        #pragma unroll
        for (int mt = 0; mt < 2; ++mt)
          #pragma unroll
          for (int ot = 0; ot < 4; ++ot) {
            acc[mt][ot][0] = 0.f; acc[mt][ot][1] = 0.f;
            acc[mt][ot][2] = 0.f; acc[mt][ot][3] = 0.f;
          }
      }
      {
        const ushort* xrow = xT + (size_t)(bid - tap) * (N * F);
        const ushort* hbase = Hb + (size_t)((e * K + tap) * 64) * 64;
        v8s xf[2][2], hf[4][2];
        #pragma unroll
        for (int mt = 0; mt < 2; ++mt) {
          const ushort* xr = xrow + ((2 * w + mt) * 16 + l15) * F;
          xf[mt][0] = *(const v8s*)(xr + q * 8);
          xf[mt][1] = *(const v8s*)(xr + 32 + q * 8);
        }
        #pragma unroll
        for (int ot = 0; ot < 4; ++ot) {
          const ushort* hr = hbase + (ot * 16 + l15) * 64;
          hf[ot][0] = *(const v8s*)(hr + q * 8);
          hf[ot][1] = *(const v8s*)(hr + 32 + q * 8);
        }
        #pragma unroll
        for (int fk = 0; fk < 2; ++fk)
          #pragma unroll
          for (int mt = 0; mt < 2; ++mt)
            #pragma unroll
            for (int ot = 0; ot < 4; ++ot)
              tgt[mt][ot] = __builtin_amdgcn_mfma_f32_16x16x32_bf16(
                  xf[mt][fk], hf[ot][fk], tgt[mt][ot], 0, 0, 0);
      }

      if (doMM) {
        __syncthreads();   // phase1 writes visible
        // phase2: read 8x8 blocks (thread (a,bg)) — conflict-free
        const int a = tid & 15, bg = tid >> 4;
        v8s rows[8];
        #pragma unroll
        for (int j = 0; j < 8; ++j)
          rows[j] = *(const v8s*)&sS[(8 * a + j) * SSW + ((bg ^ a) * 8)];
        __syncthreads();   // all reads done before in-place overwrite
        // phase3: write transposed block to [n][m], swizzled
        #pragma unroll
        for (int i = 0; i < 8; ++i) {
          uint4 wv;
          wv.x = (uint)(ushort)rows[0][i] | ((uint)(ushort)rows[1][i] << 16);
          wv.y = (uint)(ushort)rows[2][i] | ((uint)(ushort)rows[3][i] << 16);
          wv.z = (uint)(ushort)rows[4][i] | ((uint)(ushort)rows[5][i] << 16);
          wv.w = (uint)(ushort)rows[6][i] | ((uint)(ushort)rows[7][i] << 16);
          *(uint4*)&sS[(8 * bg + i) * SSW + ((a ^ bg) * 8)] = wv;
        }
        __syncthreads();   // S^T ready
        // mm: tgt += S^T @ Z
        #pragma unroll
        for (int c = 0; c < 4; ++c) {
          v8s bz[4];
          #pragma unroll
          for (int ot = 0; ot < 4; ++ot)
            bz[ot] = *(const v8s*)&sZ[(ot * 16 + l15) * SZW + c * 32 + q * 8];
          #pragma unroll
          for (int mt = 0; mt < 2; ++mt) {
            const int n = (2 * w + mt) * 16 + l15;
            const v8s af = *(const v8s*)&sS[n * SSW + ((((c << 2) | q) ^ (n >> 3)) * 8)];
            #pragma unroll
            for (int ot = 0; ot < 4; ++ot)
              tgt[mt][ot] = __builtin_amdgcn_mfma_f32_16x16x32_bf16(
                  af, bz[ot], tgt[mt][ot], 0, 0, 0);
          }
        }
      }
      have = true;
    }
  }

  // epilogue: y[b,t][o][n] = Y^T[n][o] + bias[o]
  float* yg = y + (size_t)bid * (F * N);
  #pragma unroll
  for (int ot = 0; ot < 4; ++ot) {
    const int o = ot * 16 + l15;
    const float bv = bias[o];
    #pragma unroll
    for (int mt = 0; mt < 2; ++mt) {
      float4 v;
      v.x = yacc[mt][ot][0] + bv; v.y = yacc[mt][ot][1] + bv;
      v.z = yacc[mt][ot][2] + bv; v.w = yacc[mt][ot][3] + bv;
      *(float4*)(yg + o * N + (2 * w + mt) * 16 + q * 4) = v;
    }
  }
}

extern "C" void kernel_launch(void* const* d_in, const int* in_sizes, int n_in,
                              void* d_out, int out_size, void* d_ws, size_t ws_size,
                              hipStream_t stream) {
  const float* x    = (const float*)d_in[0];
  const float* S    = (const float*)d_in[1];
  const float* H    = (const float*)d_in[2];
  const float* bias = (const float*)d_in[3];
  float* y = (float*)d_out;

  const size_t XTn = (size_t)B * T * N * F;   // 8.39M ushorts (16 MB)
  ushort* xT = (ushort*)d_ws;
  ushort* Hb = xT + XTn;                      // 32768 ushorts

  gf_prep <<<B * T + 32, 256, 0, stream>>>(x, H, xT, Hb);
  gf_chain<<<B * T,      256, 0, stream>>>(S, xT, Hb, bias, y);
}